// Round 1
// baseline (111.120 us; speedup 1.0000x reference)
//
#include <hip/hip_runtime.h>

// 1-D hash-grid embedder, 8 levels, 2 feats, fp32.
// resolution_l = 16 << l (exact powers of two), so:
//   idx = floor(x * res)          (x*res is exact: power-of-2 scale)
//   w   = x*res - idx             (== reference's (x - idx/res)/(1/res) bit-exactly)
// idx <= 2048 << hash mask 2^19-1, so the hash AND is a formality.
// Hot table region ~131 KB -> L2-resident; kernel is write-BW-bound (~256 MB out).

#define NGP_BATCH   4194304
#define NGP_LEVELS  8
#define NGP_TSIZE   (1 << 19)
#define NGP_MASK    (NGP_TSIZE - 1)

__global__ __launch_bounds__(256) void hashenc_kernel(
    const float* __restrict__ x,
    const float* __restrict__ tables,
    float* __restrict__ out)
{
    int i = blockIdx.x * blockDim.x + threadIdx.x;
    if (i >= NGP_BATCH) return;

    float xv = x[i];

    float4 o[4];
    float* op = reinterpret_cast<float*>(o);

#pragma unroll
    for (int l = 0; l < NGP_LEVELS; ++l) {
        float res  = (float)(16 << l);          // 16..2048, exact
        float fx   = xv * res;                  // exact (power-of-2 scale)
        float fidx = floorf(fx);
        float w    = fx - fidx;                 // == reference w bit-exactly
        int   idx  = (int)fidx;
        int   h0   = idx & NGP_MASK;
        int   h1   = (idx + 1) & NGP_MASK;

        const float2* tab = reinterpret_cast<const float2*>(tables) + (size_t)l * NGP_TSIZE;
        float2 e0 = tab[h0];
        float2 e1 = tab[h1];

        float om = 1.0f - w;
        op[2 * l]     = e0.x * om + e1.x * w;
        op[2 * l + 1] = e0.y * om + e1.y * w;
    }

    float4* ov = reinterpret_cast<float4*>(out + (size_t)i * 16);
    ov[0] = o[0];
    ov[1] = o[1];
    ov[2] = o[2];
    ov[3] = o[3];
}

extern "C" void kernel_launch(void* const* d_in, const int* in_sizes, int n_in,
                              void* d_out, int out_size, void* d_ws, size_t ws_size,
                              hipStream_t stream) {
    const float* x      = (const float*)d_in[0];
    const float* tables = (const float*)d_in[1];
    float*       out    = (float*)d_out;

    const int block = 256;
    const int grid  = (NGP_BATCH + block - 1) / block;   // 16384 blocks
    hashenc_kernel<<<grid, block, 0, stream>>>(x, tables, out);
}

// Round 2
// 104.390 us; speedup vs baseline: 1.0645x; 1.0645x over previous
//
#include <hip/hip_runtime.h>

// 1-D hash-grid embedder, 8 levels, 2 feats, fp32, B = 4.19M.
//
// Round-1 post-mortem: global scatter-gather was the wall (67M cache-line
// transactions / 256 CU / 2.4GHz = 109us ~= measured 111us). Only entries
// 0..res per level are reachable (idx <= 2048 << 2^19 hash mask), total
// 4088 float2 = 32.7 KB -> stage in LDS, gather from LDS instead.
//
// Numerics: resolution = 16<<l is a power of two, so fx = x*res is exact and
// w = fx - floor(fx) is bit-identical to the reference's
// (x - idx*gs)/gs. Lerp kept as e0*(1-w) + e1*w like numpy.

#define NGP_BATCH   4194304
#define NGP_LEVELS  8
#define NGP_TSIZE   (1 << 19)
#define BLOCK       512

// prefix offsets of per-level hot sizes (16<<l)+1: 17,33,65,129,257,513,1025,2049
__device__ __constant__ const int NGP_OFF[9] = {0, 17, 50, 115, 244, 501, 1014, 2039, 4088};

__global__ __launch_bounds__(BLOCK) void hashenc_kernel(
    const float* __restrict__ x,
    const float* __restrict__ tables,
    float* __restrict__ out)
{
    __shared__ float2 sm[4088];   // 32704 B: all reachable table entries, all levels
    const int tid = threadIdx.x;

    // ---- stage hot table region: level l entries 0..(16<<l) ----
#pragma unroll
    for (int l = 0; l < NGP_LEVELS; ++l) {
        const int n = (16 << l) + 1;
        const float2* __restrict__ src =
            reinterpret_cast<const float2*>(tables) + (size_t)l * NGP_TSIZE;
        const int off = NGP_OFF[l];
        for (int e = tid; e < n; e += BLOCK)
            sm[off + e] = src[e];
    }
    __syncthreads();

    const int i = blockIdx.x * BLOCK + tid;   // BATCH % BLOCK == 0, no tail
    const float xv = x[i];

    float4 o[4];
    float* op = reinterpret_cast<float*>(o);

#pragma unroll
    for (int l = 0; l < NGP_LEVELS; ++l) {
        const float res  = (float)(16 << l);   // exact power-of-2 scale
        const float fx   = xv * res;           // exact
        const float fidx = floorf(fx);
        const float w    = fx - fidx;          // == reference w bit-exactly
        const int   idx  = (int)fidx;          // 0..res-1 (x < 1), idx+1 <= res staged

        const float2 e0 = sm[NGP_OFF[l] + idx];
        const float2 e1 = sm[NGP_OFF[l] + idx + 1];

        const float om = 1.0f - w;
        op[2 * l]     = e0.x * om + e1.x * w;
        op[2 * l + 1] = e0.y * om + e1.y * w;
    }

    float4* ov = reinterpret_cast<float4*>(out + (size_t)i * 16);
    ov[0] = o[0];
    ov[1] = o[1];
    ov[2] = o[2];
    ov[3] = o[3];
}

extern "C" void kernel_launch(void* const* d_in, const int* in_sizes, int n_in,
                              void* d_out, int out_size, void* d_ws, size_t ws_size,
                              hipStream_t stream) {
    const float* x      = (const float*)d_in[0];
    const float* tables = (const float*)d_in[1];
    float*       out    = (float*)d_out;

    const int grid = NGP_BATCH / BLOCK;   // 8192 blocks
    hashenc_kernel<<<grid, BLOCK, 0, stream>>>(x, tables, out);
}

// Round 3
// 66.325 us; speedup vs baseline: 1.6754x; 1.5739x over previous
//
#include <hip/hip_runtime.h>

// 1-D hash-grid embedder, 8 levels, 2 feats, fp32, B = 4.19M.
//
// Round-2 post-mortem: LDS-staging the gathers only gave 111->104us, so the
// wall is shared: (a) per-point 64B-strided float4 stores fragment every wave
// store into ~64 line-segments, (b) 16 random ds_read_b64/point conflict ~8-way.
//
// This version: 4 threads per point. Thread (q=tid>>2, s=tid&3) computes level
// pair {2s,2s+1} = one output float4 at index p*4+s = base+tid -> every wave
// store is a contiguous 1KB burst. Tables staged as duplicated float4 pairs
// {t[e],t[e+1]} so each level is ONE ds_read_b128 (8 LDS reads/point, was 16).
//
// Numerics unchanged from the passing rounds: res = 16<<l is a power of two,
// fx = x*res exact, w = fx - floor(fx) bit-identical to reference.

#define NGP_BATCH   4194304
#define NGP_TSIZE   (1 << 19)
#define BLOCK       512
#define PPB         1024              // points per block
#define KITER       (PPB / (BLOCK/4)) // 8 points per thread

__global__ __launch_bounds__(BLOCK) void hashenc_kernel(
    const float* __restrict__ x,
    const float* __restrict__ tables,
    float* __restrict__ out)
{
    // level l occupies off4(l) = 16*((1<<l)-1), size 16<<l float4 entries
    __shared__ float4 sm4[4080];   // 65280 B

    const int tid = threadIdx.x;

    // ---- stage duplicated pairs: sm4[off+e] = {t[e].x,t[e].y,t[e+1].x,t[e+1].y}
#pragma unroll
    for (int l = 0; l < 8; ++l) {
        const int n   = 16 << l;                 // idx <= n-1 since x < 1
        const int off = 16 * ((1 << l) - 1);
        const float2* __restrict__ src =
            reinterpret_cast<const float2*>(tables) + (size_t)l * NGP_TSIZE;
        for (int e = tid; e < n; e += BLOCK) {
            const float2 a = src[e];
            const float2 b = src[e + 1];
            sm4[off + e] = make_float4(a.x, a.y, b.x, b.y);
        }
    }
    __syncthreads();

    const int q  = tid >> 2;
    const int s  = tid & 3;
    const int l0 = 2 * s;
    const int l1 = 2 * s + 1;
    const float res0 = (float)(16 << l0);
    const float res1 = (float)(16 << l1);
    const int   off0 = 16 * ((1 << l0) - 1);
    const int   off1 = 16 * ((1 << l1) - 1);

    const int P0 = blockIdx.x * PPB;
    float4* __restrict__ out4 = reinterpret_cast<float4*>(out);

#pragma unroll
    for (int k = 0; k < KITER; ++k) {
        const int   p  = P0 + q + 128 * k;
        const float xv = x[p];

        const float fx0 = xv * res0;             // exact pow2 scale
        const float fi0 = floorf(fx0);
        const float w0  = fx0 - fi0;             // == reference w
        const float4 e0 = sm4[off0 + (int)fi0];

        const float fx1 = xv * res1;
        const float fi1 = floorf(fx1);
        const float w1  = fx1 - fi1;
        const float4 e1 = sm4[off1 + (int)fi1];

        float4 r;
        r.x = e0.x * (1.0f - w0) + e0.z * w0;
        r.y = e0.y * (1.0f - w0) + e0.w * w0;
        r.z = e1.x * (1.0f - w1) + e1.z * w1;
        r.w = e1.y * (1.0f - w1) + e1.w * w1;

        out4[(size_t)p * 4 + s] = r;             // = base + tid: contiguous 1KB/wave
    }
}

extern "C" void kernel_launch(void* const* d_in, const int* in_sizes, int n_in,
                              void* d_out, int out_size, void* d_ws, size_t ws_size,
                              hipStream_t stream) {
    const float* x      = (const float*)d_in[0];
    const float* tables = (const float*)d_in[1];
    float*       out    = (float*)d_out;

    const int grid = NGP_BATCH / PPB;   // 4096 blocks
    hashenc_kernel<<<grid, BLOCK, 0, stream>>>(x, tables, out);
}

// Round 5
// 57.348 us; speedup vs baseline: 1.9376x; 1.1565x over previous
//
#include <hip/hip_runtime.h>

// 1-D hash-grid embedder, 8 levels, 2 feats, fp32, B = 4.19M.
//
// Round-3 post-mortem: 4-thread-per-point + b128 LDS gather + coalesced 1KB
// wave stores got 104->66us, but fills hit 7 TB/s at 10% occupancy, so the
// residual is NOT latency hiding -- it's the 65KB staging prologue replicated
// 4096x (~1us prologue per ~3us of streaming, plus per-block ramp).
//
// This version: persistent-style blocks. 512 blocks (exactly 2/CU, 130KB LDS),
// 64 iterations each -> staging amortized 8x. Nontemporal stores keep the
// output stream from thrashing the L2-resident hot tables.
// (Round-4 fix: __builtin_nontemporal_store needs a native vector type, not
// HIP's float4 class -> ext_vector_type(4) alias.)
//
// Numerics: res = 16<<l is a power of two, fx = x*res exact,
// w = fx - floor(fx) bit-identical to the reference's (x - idx*gs)/gs.

#define NGP_BATCH   4194304
#define NGP_TSIZE   (1 << 19)
#define BLOCK       512
#define PPB         8192                // points per block
#define KITER       (PPB / (BLOCK/4))   // 64 iterations of 128 points

typedef float f32x4 __attribute__((ext_vector_type(4)));

__global__ __launch_bounds__(BLOCK) void hashenc_kernel(
    const float* __restrict__ x,
    const float* __restrict__ tables,
    float* __restrict__ out)
{
    // level l at off4(l) = 16*((1<<l)-1), size 16<<l float4 (duplicated pairs)
    __shared__ float4 sm4[4080];   // 65280 B -> 2 blocks/CU

    const int tid = threadIdx.x;

    // ---- stage duplicated pairs: sm4[off+e] = {t[e].x,t[e].y,t[e+1].x,t[e+1].y}
#pragma unroll
    for (int l = 0; l < 8; ++l) {
        const int n   = 16 << l;                 // idx <= n-1 since x < 1
        const int off = 16 * ((1 << l) - 1);
        const float2* __restrict__ src =
            reinterpret_cast<const float2*>(tables) + (size_t)l * NGP_TSIZE;
        for (int e = tid; e < n; e += BLOCK) {
            const float2 a = src[e];
            const float2 b = src[e + 1];
            sm4[off + e] = make_float4(a.x, a.y, b.x, b.y);
        }
    }
    __syncthreads();

    const int q  = tid >> 2;
    const int s  = tid & 3;
    const int l0 = 2 * s;
    const int l1 = 2 * s + 1;
    const float res0 = (float)(16 << l0);
    const float res1 = (float)(16 << l1);
    const int   off0 = 16 * ((1 << l0) - 1);
    const int   off1 = 16 * ((1 << l1) - 1);

    const int P0 = blockIdx.x * PPB;
    f32x4* __restrict__ out4 = reinterpret_cast<f32x4*>(out);

#pragma unroll 4
    for (int k = 0; k < KITER; ++k) {
        const int   p  = P0 + q + 128 * k;
        const float xv = x[p];

        const float fx0 = xv * res0;             // exact pow2 scale
        const float fi0 = floorf(fx0);
        const float w0  = fx0 - fi0;             // == reference w
        const float4 e0 = sm4[off0 + (int)fi0];

        const float fx1 = xv * res1;
        const float fi1 = floorf(fx1);
        const float w1  = fx1 - fi1;
        const float4 e1 = sm4[off1 + (int)fi1];

        f32x4 r;
        r.x = e0.x * (1.0f - w0) + e0.z * w0;
        r.y = e0.y * (1.0f - w0) + e0.w * w0;
        r.z = e1.x * (1.0f - w1) + e1.z * w1;
        r.w = e1.y * (1.0f - w1) + e1.w * w1;

        __builtin_nontemporal_store(r, &out4[(size_t)p * 4 + s]);  // 1KB/wave burst
    }
}

extern "C" void kernel_launch(void* const* d_in, const int* in_sizes, int n_in,
                              void* d_out, int out_size, void* d_ws, size_t ws_size,
                              hipStream_t stream) {
    const float* x      = (const float*)d_in[0];
    const float* tables = (const float*)d_in[1];
    float*       out    = (float*)d_out;

    const int grid = NGP_BATCH / PPB;   // 512 blocks = 2 per CU
    hashenc_kernel<<<grid, BLOCK, 0, stream>>>(x, tables, out);
}